// Round 1
// baseline (216.440 us; speedup 1.0000x reference)
//
#include <hip/hip_runtime.h>
#include <math.h>

#define T_DIM  1024
#define B_DIM  8
#define IN_D   512
#define NROWS  (T_DIM * B_DIM)      // 8192
#define EPSF   1e-8f
#define LOG_EPS (-18.4206807f)      // logf(1e-8)

#define CHUNK  16
#define NCHUNK (T_DIM / CHUNK)      // 64
#define SEG    16
#define NSEG   (T_DIM / SEG)        // 64

typedef float vfloat4 __attribute__((ext_vector_type(4)));

// ---- workspace layout (floats) ----
#define OFF_WT   0                                  // 512*192      = 98304
#define OFF_V    (OFF_WT + IN_D * 192)
#define OFF_K    (OFF_V  + NROWS * 64)              // raw k (never overwritten now)
#define OFF_Z    (OFF_K  + NROWS * 64)              // log alpha (written by K1)
#define OFF_SEG  (OFF_Z  + NROWS * 64)              // 64*512 segment sums (atomic)
#define OFF_TOT  (OFF_SEG + NSEG * B_DIM * 64)      // unused, kept for layout stability
#define OFF_P    (OFF_TOT + B_DIM * 64)             // 64*8*4096 = 2097152

// K0: concat+transpose weights -> Wt[i][c], i<512, c<192. Also zero seg (atomic targets).
__global__ void k0_wt(const float* __restrict__ Wv, const float* __restrict__ Wk,
                      const float* __restrict__ Wa, float* __restrict__ Wt,
                      float* __restrict__ seg) {
    int idx = blockIdx.x * 256 + threadIdx.x;       // < 98304
    if (idx < NSEG * 512) seg[idx] = 0.f;
    int i = idx / 192, c = idx % 192;
    float v;
    if (c < 64)       v = Wv[c * IN_D + i];
    else if (c < 128) v = Wk[(c - 64) * IN_D + i];
    else              v = Wa[(c - 128) * IN_D + i];
    Wt[i * 192 + c] = v;
}

// K1: projections, all-b128 LDS. 256 blocks x 256 thr; block = 32 rows, K-split-2.
// Epilogue now also computes log(max(sigmoid(z),eps)) for the alpha matrix, stores it
// to Zb, and atomically accumulates 16-step segment sums into seg. This deletes K2a.
__global__ __launch_bounds__(256) void k1_proj(
        const float* __restrict__ x, const float* __restrict__ Wt,
        const float* __restrict__ bv, const float* __restrict__ bk, const float* __restrict__ ba,
        float* __restrict__ V, float* __restrict__ Kb, float* __restrict__ Zb,
        float* __restrict__ seg) {
    __shared__ float xs[2][32][32];     // [half][kk][row] 8 KB, transposed x
    __shared__ float wsm[2][32][192];   // [half][kk][col] 48 KB
    const int tid  = threadIdx.x;
    const int h    = tid >> 7;          // K half: 0 -> K[0:256), 1 -> K[256:512)
    const int t7   = tid & 127;
    const int rq   = t7 >> 4;           // row quad 0..7
    const int cq   = t7 & 15;           // col quad 0..15
    const int row0 = blockIdx.x * 32;

    float4 acc[4][3];
#pragma unroll
    for (int j = 0; j < 4; ++j)
#pragma unroll
        for (int m = 0; m < 3; ++m) acc[j][m] = make_float4(0.f, 0.f, 0.f, 0.f);

    for (int s = 0; s < 8; ++s) {       // K-slice of 32 per half
#pragma unroll
        for (int q = 0; q < 2; ++q) {
            int idx = tid + q * 256;            // 0..511
            int hh = idx >> 8, r = idx & 31, f = (idx >> 5) & 7;
            float4 v4 = reinterpret_cast<const float4*>(x)[((row0 + r) * IN_D + hh * 256 + s * 32 + f * 4) >> 2];
            xs[hh][f * 4 + 0][r] = v4.x;
            xs[hh][f * 4 + 1][r] = v4.y;
            xs[hh][f * 4 + 2][r] = v4.z;
            xs[hh][f * 4 + 3][r] = v4.w;
        }
#pragma unroll
        for (int q = 0; q < 12; ++q) {
            int idx = tid + q * 256;            // 0..3071
            int hh = idx / 1536;
            int rem = idx - hh * 1536;
            int kk = rem / 48;
            int f  = rem - kk * 48;
            float4 v4 = reinterpret_cast<const float4*>(Wt)[((hh * 256 + s * 32 + kk) * 192 + f * 4) >> 2];
            *reinterpret_cast<float4*>(&wsm[hh][kk][f * 4]) = v4;
        }
        __syncthreads();

#pragma unroll 4
        for (int kk = 0; kk < 32; ++kk) {
            float4 xv = *reinterpret_cast<const float4*>(&xs[h][kk][rq * 4]);
#pragma unroll
            for (int m = 0; m < 3; ++m) {
                float4 wq = *reinterpret_cast<const float4*>(&wsm[h][kk][m * 64 + cq * 4]);
#pragma unroll
                for (int j = 0; j < 4; ++j) {
                    float xx = (&xv.x)[j];
                    acc[j][m].x = fmaf(xx, wq.x, acc[j][m].x);
                    acc[j][m].y = fmaf(xx, wq.y, acc[j][m].y);
                    acc[j][m].z = fmaf(xx, wq.z, acc[j][m].z);
                    acc[j][m].w = fmaf(xx, wq.w, acc[j][m].w);
                }
            }
        }
        __syncthreads();
    }

    // cross-half reduce via LDS (reuse wsm; stride 52 floats to dodge bank conflicts)
    float* red = &wsm[0][0][0];
    if (h == 1) {
#pragma unroll
        for (int j = 0; j < 4; ++j)
#pragma unroll
            for (int m = 0; m < 3; ++m)
                *reinterpret_cast<float4*>(&red[t7 * 52 + (j * 3 + m) * 4]) = acc[j][m];
    }
    __syncthreads();
    if (h == 0) {
        float4 bv4 = *reinterpret_cast<const float4*>(&bv[cq * 4]);
        float4 bk4 = *reinterpret_cast<const float4*>(&bk[cq * 4]);
        float4 ba4 = *reinterpret_cast<const float4*>(&ba[cq * 4]);
#pragma unroll
        for (int j = 0; j < 4; ++j) {
            int row = row0 + rq * 4 + j;
            float4 o0 = *reinterpret_cast<const float4*>(&red[t7 * 52 + (j * 3 + 0) * 4]);
            float4 o1 = *reinterpret_cast<const float4*>(&red[t7 * 52 + (j * 3 + 1) * 4]);
            float4 o2 = *reinterpret_cast<const float4*>(&red[t7 * 52 + (j * 3 + 2) * 4]);
            float4 r0, r1, z2, l4;
            r0.x = acc[j][0].x + o0.x + bv4.x; r0.y = acc[j][0].y + o0.y + bv4.y;
            r0.z = acc[j][0].z + o0.z + bv4.z; r0.w = acc[j][0].w + o0.w + bv4.w;
            r1.x = acc[j][1].x + o1.x + bk4.x; r1.y = acc[j][1].y + o1.y + bk4.y;
            r1.z = acc[j][1].z + o1.z + bk4.z; r1.w = acc[j][1].w + o1.w + bk4.w;
            z2.x = acc[j][2].x + o2.x + ba4.x; z2.y = acc[j][2].y + o2.y + ba4.y;
            z2.z = acc[j][2].z + o2.z + ba4.z; z2.w = acc[j][2].w + o2.w + ba4.w;
            // log(max(sigmoid(z),eps)) = max(-log1p(exp(-z)), log(eps))
            l4.x = fmaxf(-log1pf(expf(-z2.x)), LOG_EPS);
            l4.y = fmaxf(-log1pf(expf(-z2.y)), LOG_EPS);
            l4.z = fmaxf(-log1pf(expf(-z2.z)), LOG_EPS);
            l4.w = fmaxf(-log1pf(expf(-z2.w)), LOG_EPS);
            *reinterpret_cast<float4*>(&V [row * 64 + cq * 4]) = r0;
            *reinterpret_cast<float4*>(&Kb[row * 64 + cq * 4]) = r1;
            *reinterpret_cast<float4*>(&Zb[row * 64 + cq * 4]) = l4;
            int sg = row >> 7;                      // t>>4 = segment
            float* sp = &seg[sg * 512 + (row & 7) * 64 + cq * 4];
            atomicAdd(sp + 0, l4.x);
            atomicAdd(sp + 1, l4.y);
            atomicAdd(sp + 2, l4.z);
            atomicAdd(sp + 3, l4.w);
        }
    }
}

// Phase-A helper idea (inlined in K3/K5): each block (b,cch) recomputes its own
// w[t] = k[t]*exp(cumlog[t])/(exp(total)+eps) tile directly into LDS staging.
// Replaces K2b (single-block scan) + K2c entirely.

// K3: per-chunk partial outer sums P[c][b][d][n]. 512 blocks (b,c) x 256 thr.
__global__ __launch_bounds__(256) void k3_partial(const float* __restrict__ V,
                                                  const float* __restrict__ Z,
                                                  const float* __restrict__ seg,
                                                  const float* __restrict__ Kb,
                                                  float* __restrict__ P) {
    __shared__ float vs[CHUNK * 64];
    __shared__ float wsh[CHUNK * 64];
    __shared__ float gsum[4 * 64];
    int b = blockIdx.x & 7, cch = blockIdx.x >> 3;
    int tid = threadIdx.x;
    int dg = tid >> 4, n4 = tid & 15;
    int n = tid & 63, g = tid >> 6;
    int base = b * 64 + n;

    // early V stage load
    int il = tid >> 4, f = tid & 15;
    float4 v4 = reinterpret_cast<const float4*>(V)[((cch * CHUNK + il) * 8 + b) * 16 + f];

    // cross-segment exclusive prefix + total (seg is 131 KB, L2-resident; coalesced 256B/iter)
    float run = 0.f, total = 0.f;
#pragma unroll 8
    for (int s2 = 0; s2 < NSEG; ++s2) {
        float sv = seg[s2 * 512 + base];
        if (s2 < cch) run += sv;
        total += sv;
    }
    float invden = 1.f / (expf(total) + EPSF);

    int t0 = cch * CHUNK + g * 4;
    float l0 = Z[(t0 + 0) * 512 + base];
    float l1 = Z[(t0 + 1) * 512 + base];
    float l2 = Z[(t0 + 2) * 512 + base];
    float l3 = Z[(t0 + 3) * 512 + base];
    float k0v = Kb[(t0 + 0) * 512 + base];
    float k1v = Kb[(t0 + 1) * 512 + base];
    float k2v = Kb[(t0 + 2) * 512 + base];
    float k3v = Kb[(t0 + 3) * 512 + base];
    gsum[g * 64 + n] = l0 + l1 + l2 + l3;
    reinterpret_cast<float4*>(vs)[il * 16 + f] = v4;
    __syncthreads();
    float pre = run;
#pragma unroll
    for (int g2 = 0; g2 < 3; ++g2) if (g2 < g) pre += gsum[g2 * 64 + n];
    float c0 = pre + l0, c1 = c0 + l1, c2 = c1 + l2, c3 = c2 + l3;
    wsh[(g * 4 + 0) * 64 + n] = k0v * expf(c0) * invden;
    wsh[(g * 4 + 1) * 64 + n] = k1v * expf(c1) * invden;
    wsh[(g * 4 + 2) * 64 + n] = k2v * expf(c2) * invden;
    wsh[(g * 4 + 3) * 64 + n] = k3v * expf(c3) * invden;
    __syncthreads();

    float4 acc[4];
#pragma unroll
    for (int q = 0; q < 4; ++q) acc[q] = make_float4(0.f, 0.f, 0.f, 0.f);

#pragma unroll
    for (int i = 0; i < CHUNK; ++i) {
        float4 wv = reinterpret_cast<const float4*>(wsh)[i * 16 + n4];
#pragma unroll
        for (int q = 0; q < 4; ++q) {
            float vd = vs[i * 64 + dg + 16 * q];
            acc[q].x = fmaf(vd, wv.x, acc[q].x);
            acc[q].y = fmaf(vd, wv.y, acc[q].y);
            acc[q].z = fmaf(vd, wv.z, acc[q].z);
            acc[q].w = fmaf(vd, wv.w, acc[q].w);
        }
    }
    float* Pp = P + (cch * 8 + b) * 4096;
#pragma unroll
    for (int q = 0; q < 4; ++q)
        *reinterpret_cast<float4*>(Pp + (dg + 16 * q) * 64 + 4 * n4) = acc[q];
}

// K4: exclusive prefix over 64 chunks, in place. 128 blocks x 256 thr.
__global__ __launch_bounds__(256) void k4_prefix(float* __restrict__ P) {
    int gid = blockIdx.x * 256 + threadIdx.x;   // < 32768
    int b = gid >> 12, dn = gid & 4095;
    float run = 0.f;
#pragma unroll
    for (int c = 0; c < NCHUNK; ++c) {
        float v = P[(c * 8 + b) * 4096 + dn];
        P[(c * 8 + b) * 4096 + dn] = run;
        run += v;
    }
}

// K5: recompute w tile (phase A) + main cumsum + streaming store (134 MB). 512 blocks x 256 thr.
__global__ __launch_bounds__(256) void k5_main(const float* __restrict__ V,
                                               const float* __restrict__ Z,
                                               const float* __restrict__ seg,
                                               const float* __restrict__ Kb,
                                               const float* __restrict__ P,
                                               float* __restrict__ S) {
    __shared__ float vs[CHUNK * 64];
    __shared__ float wsh[CHUNK * 64];
    __shared__ float gsum[4 * 64];
    int b = blockIdx.x & 7, cch = blockIdx.x >> 3;
    int tid = threadIdx.x;
    int dg = tid >> 4, n4 = tid & 15;
    int n = tid & 63, g = tid >> 6;
    int base = b * 64 + n;

    // early loads: V stage + P accumulator init
    int il = tid >> 4, f = tid & 15;
    float4 v4 = reinterpret_cast<const float4*>(V)[((cch * CHUNK + il) * 8 + b) * 16 + f];
    vfloat4 acc[4];
    const float* Pp = P + (cch * 8 + b) * 4096;
#pragma unroll
    for (int q = 0; q < 4; ++q)
        acc[q] = *reinterpret_cast<const vfloat4*>(Pp + (dg + 16 * q) * 64 + 4 * n4);

    // phase A: recompute w tile
    float run = 0.f, total = 0.f;
#pragma unroll 8
    for (int s2 = 0; s2 < NSEG; ++s2) {
        float sv = seg[s2 * 512 + base];
        if (s2 < cch) run += sv;
        total += sv;
    }
    float invden = 1.f / (expf(total) + EPSF);

    int t0 = cch * CHUNK + g * 4;
    float l0 = Z[(t0 + 0) * 512 + base];
    float l1 = Z[(t0 + 1) * 512 + base];
    float l2 = Z[(t0 + 2) * 512 + base];
    float l3 = Z[(t0 + 3) * 512 + base];
    float k0v = Kb[(t0 + 0) * 512 + base];
    float k1v = Kb[(t0 + 1) * 512 + base];
    float k2v = Kb[(t0 + 2) * 512 + base];
    float k3v = Kb[(t0 + 3) * 512 + base];
    gsum[g * 64 + n] = l0 + l1 + l2 + l3;
    reinterpret_cast<float4*>(vs)[il * 16 + f] = v4;
    __syncthreads();
    float pre = run;
#pragma unroll
    for (int g2 = 0; g2 < 3; ++g2) if (g2 < g) pre += gsum[g2 * 64 + n];
    float c0 = pre + l0, c1 = c0 + l1, c2 = c1 + l2, c3 = c2 + l3;
    wsh[(g * 4 + 0) * 64 + n] = k0v * expf(c0) * invden;
    wsh[(g * 4 + 1) * 64 + n] = k1v * expf(c1) * invden;
    wsh[(g * 4 + 2) * 64 + n] = k2v * expf(c2) * invden;
    wsh[(g * 4 + 3) * 64 + n] = k3v * expf(c3) * invden;
    __syncthreads();

#pragma unroll
    for (int i = 0; i < CHUNK; ++i) {
        float4 wv = reinterpret_cast<const float4*>(wsh)[i * 16 + n4];
        int t = cch * CHUNK + i;
        float* Sb = S + (size_t)t * 32768 + b * 4096;
#pragma unroll
        for (int q = 0; q < 4; ++q) {
            float vd = vs[i * 64 + dg + 16 * q];
            acc[q].x = fmaf(vd, wv.x, acc[q].x);
            acc[q].y = fmaf(vd, wv.y, acc[q].y);
            acc[q].z = fmaf(vd, wv.z, acc[q].z);
            acc[q].w = fmaf(vd, wv.w, acc[q].w);
            __builtin_nontemporal_store(acc[q],
                reinterpret_cast<vfloat4*>(Sb + (dg + 16 * q) * 64 + 4 * n4));
        }
    }
}

extern "C" void kernel_launch(void* const* d_in, const int* in_sizes, int n_in,
                              void* d_out, int out_size, void* d_ws, size_t ws_size,
                              hipStream_t stream) {
    const float* x  = (const float*)d_in[0];
    const float* Wv = (const float*)d_in[1];
    const float* bv = (const float*)d_in[2];
    const float* Wk = (const float*)d_in[3];
    const float* bk = (const float*)d_in[4];
    const float* Wa = (const float*)d_in[5];
    const float* ba = (const float*)d_in[6];
    float* S  = (float*)d_out;
    float* ws = (float*)d_ws;

    float* Wt  = ws + OFF_WT;
    float* V   = ws + OFF_V;
    float* Kb  = ws + OFF_K;
    float* Zb  = ws + OFF_Z;
    float* seg = ws + OFF_SEG;
    float* P   = ws + OFF_P;

    k0_wt     <<<384, 256, 0, stream>>>(Wv, Wk, Wa, Wt, seg);
    k1_proj   <<<256, 256, 0, stream>>>(x, Wt, bv, bk, ba, V, Kb, Zb, seg);
    k3_partial<<<512, 256, 0, stream>>>(V, Zb, seg, Kb, P);
    k4_prefix <<<128, 256, 0, stream>>>(P);
    k5_main   <<<512, 256, 0, stream>>>(V, Zb, seg, Kb, P, S);
}